// Round 13
// baseline (2786.079 us; speedup 1.0000x reference)
//
#include <hip/hip_runtime.h>
#include <hip/hip_bf16.h>
#include <math.h>

// Problem constants (B,T,H,V) = (2,1024,4096,32000)
#define TT 1024
#define MM 2048      // B*T tokens
#define HH 4096
#define VV 32000
#define BETA_ 0.1f
#define NPB (VV/64)  // 500 partial (max,sumexp) blocks per token row

// GEMM geometry
#define BM 256
#define BN 256
#define BK 64
#define NT (HH/BK)   // 64 K-tiles

typedef short short8 __attribute__((ext_vector_type(8)));
typedef float f32x4 __attribute__((ext_vector_type(4)));
typedef unsigned u32x2 __attribute__((ext_vector_type(2)));

__device__ inline unsigned f2bf1(float f) {
    union { float f; unsigned u; } v; v.f = f;
    return (v.u + 0x7fffu + ((v.u >> 16) & 1u)) >> 16;   // RNE f32->bf16
}
__device__ inline uint2 pack4(float4 a) {
    uint2 r;
    r.x = f2bf1(a.x) | (f2bf1(a.y) << 16);
    r.y = f2bf1(a.z) | (f2bf1(a.w) << 16);
    return r;
}
// RNE pack via v_cvt_pk_bf16_f32 (identical rounding to f2bf1).
__device__ inline unsigned cvtpk(float lo, float hi) {
    union { __hip_bfloat162 h; unsigned u; } v;
    v.h = __float22bfloat162_rn(make_float2(lo, hi));
    return v.u;
}

// global -> LDS direct copy, 16B per lane. LDS dest is wave-uniform base + lane*16.
__device__ __forceinline__ void gload_lds16(const void* g, void* l) {
    __builtin_amdgcn_global_load_lds(
        (const __attribute__((address_space(1))) void*)(uintptr_t)g,
        (__attribute__((address_space(3))) void*)(unsigned)(uintptr_t)l,
        16, 0, 0);
}

// ---------------- fp32 -> bf16 pre-conversion (8 elem / thread / iter) ------
__global__ __launch_bounds__(256) void conv_bf16(
    const float* __restrict__ src, unsigned short* __restrict__ dst, int n8)
{
    int i = blockIdx.x * 256 + threadIdx.x;
    const int stride = gridDim.x * 256;
    for (; i < n8; i += stride) {
        const float4* s = (const float4*)src + 2 * (size_t)i;
        float4 a = s[0], b = s[1];
        uint2 lo = pack4(a), hi = pack4(b);
        *(uint4*)(dst + (size_t)i * 8) = make_uint4(lo.x, lo.y, hi.x, hi.y);
    }
}

#define SBAR()                                                                \
    __builtin_amdgcn_sched_barrier(0);                                        \
    __builtin_amdgcn_s_barrier();                                             \
    __builtin_amdgcn_sched_barrier(0);

#define MFMA16(AF, BF, MB, NB)                                                \
    _Pragma("unroll") for (int m_ = 0; m_ < 4; ++m_)                          \
    _Pragma("unroll") for (int n_ = 0; n_ < 2; ++n_)                          \
    _Pragma("unroll") for (int kk_ = 0; kk_ < 2; ++kk_)                       \
        acc[(MB) + m_][(NB) + n_] = __builtin_amdgcn_mfma_f32_16x16x32_bf16(  \
            AF[m_][kk_], BF[n_][kk_], acc[(MB) + m_][(NB) + n_], 0, 0, 0);

#define GEMM_EPILOGUE_256                                                     \
    const int nb = (tile_n >> 6) + wc;                                        \
    _Pragma("unroll")                                                         \
    for (int mi = 0; mi < 8; ++mi) {                                          \
        _Pragma("unroll")                                                     \
        for (int r = 0; r < 4; ++r) {                                         \
            float v0 = acc[mi][0][r], v1 = acc[mi][1][r];                     \
            float v2 = acc[mi][2][r], v3 = acc[mi][3][r];                     \
            float mx = fmaxf(fmaxf(v0, v1), fmaxf(v2, v3));                   \
            _Pragma("unroll")                                                 \
            for (int d = 1; d < 16; d <<= 1)                                  \
                mx = fmaxf(mx, __shfl_xor(mx, d, 64));                        \
            float s = __expf(v0 - mx) + __expf(v1 - mx) +                     \
                      __expf(v2 - mx) + __expf(v3 - mx);                      \
            _Pragma("unroll")                                                 \
            for (int d = 1; d < 16; d <<= 1) s += __shfl_xor(s, d, 64);       \
            if (lrow == 0) {                                                  \
                int rowg = tile_m + wr * 128 + mi * 16 + lgrp * 4 + r;        \
                part[(size_t)rowg * NPB + nb] = make_float2(mx, s);           \
            }                                                                 \
        }                                                                     \
    }

// ===== v11: round-6 2-phase GEMM + side-convert (banked; GEMM-1 only) ======
// Ledger: see round-12. CONV=true streams RW fp32 -> RWbf (FIFO-clean cvLd
// after A-stages, nontemporal, store youngest, vmcnt(6)).
template<bool CONV>
__global__ __launch_bounds__(512, 2) void kto_logits_lse_v11(
    const unsigned short* __restrict__ Xb, const unsigned short* __restrict__ Wb,
    float2* __restrict__ part,
    const float* __restrict__ csrc, unsigned short* __restrict__ cdst)
{
    __shared__ __align__(16) unsigned char lds[131072];  // A: 2x32KB | B: 2x32KB

    const int tid  = threadIdx.x;
    const int lane = tid & 63;
    const int wave = tid >> 6;
    const int wr   = wave >> 2;
    const int wc   = wave & 3;
    const int lrow = lane & 15;
    const int lgrp = lane >> 4;

    const int fid  = blockIdx.y * gridDim.x + blockIdx.x;
    const int swz  = (fid & 7) * 125 + (fid >> 3);
    const int tile_m = (swz & 7) * BM;
    const int tile_n = (swz >> 3) * BN;

    const int scol = ((lane & 7) * 8) ^ ((lane >> 3) << 3);

    f32x4 acc[8][4];
#pragma unroll
    for (int i = 0; i < 8; ++i)
#pragma unroll
        for (int j = 0; j < 4; ++j) acc[i][j] = f32x4{0.f, 0.f, 0.f, 0.f};

#define STAGE_HALF(S)                                                         \
    do { int s_ = (S);                                                        \
        if (s_ < 4 * NT) {                                                    \
            int ts_ = s_ >> 2, kind_ = s_ & 3, buf_ = ts_ & 1;                \
            int isA_ = kind_ >> 1, half_ = kind_ & 1;                         \
            const unsigned short* base_ = isA_                                \
                ? Xb + (size_t)tile_m * HH : Wb + (size_t)tile_n * HH;        \
            unsigned char* lb_ = lds + (isA_ ? 0 : 65536) + buf_ * 32768;     \
            _Pragma("unroll")                                                 \
            for (int c_ = 0; c_ < 2; ++c_) {                                  \
                int rt_ = half_ * 128 + wave * 16 + c_ * 8;                   \
                gload_lds16(base_ + (size_t)(rt_ + (lane >> 3)) * HH          \
                                  + ts_ * 64 + scol,                          \
                            lb_ + rt_ * 128);                                 \
            }                                                                 \
        } } while (0)

#define LOAD_A11(DST, MH)                                                     \
    _Pragma("unroll") for (int m_ = 0; m_ < 4; ++m_)                          \
    _Pragma("unroll") for (int kk_ = 0; kk_ < 2; ++kk_) {                     \
        int rr_ = wr * 128 + (MH) * 64 + m_ * 16 + lrow;                      \
        DST[m_][kk_] = *(const short8*)(ldsAp + rr_ * 128 +                   \
            ((kk_ * 64 + lgrp * 16) ^ ((rr_ & 7) << 4))); }

#define LOAD_B11(DST, NH)                                                     \
    _Pragma("unroll") for (int n_ = 0; n_ < 2; ++n_)                          \
    _Pragma("unroll") for (int kk_ = 0; kk_ < 2; ++kk_) {                     \
        int rb_ = wc * 64 + (NH) * 32 + n_ * 16 + lrow;                       \
        DST[n_][kk_] = *(const short8*)(ldsBp + rb_ * 128 +                   \
            ((kk_ * 64 + lgrp * 16) ^ ((rb_ & 7) << 4))); }

    f32x4 cv, cvn;

#pragma unroll
    for (int s = 0; s < 6; ++s) STAGE_HALF(s);
    if (CONV) {
        cv = __builtin_nontemporal_load(
            (const f32x4*)(csrc + (size_t)fid * NT * 2048 + tid * 4));
        asm volatile("s_waitcnt vmcnt(5)" ::: "memory");
    } else {
        asm volatile("s_waitcnt vmcnt(4)" ::: "memory");
    }
    SBAR();

    for (int t = 0; t < NT; ++t) {
        const int p = t & 1;
        const unsigned char* ldsAp = lds + p * 32768;
        const unsigned char* ldsBp = lds + 65536 + p * 32768;
        short8 afa[4][2], afb[4][2], bfa[2][2], bfb[2][2];

        // ---- Phase A ----
        STAGE_HALF(4 * t + 6);
        STAGE_HALF(4 * t + 7);
        if (CONV && t + 1 < NT)
            cvn = __builtin_nontemporal_load(
                (const f32x4*)(csrc + ((size_t)fid * NT + t + 1) * 2048 + tid * 4));
        LOAD_A11(afa, 0);
        LOAD_B11(bfa, 0);
        LOAD_B11(bfb, 1);
        __builtin_amdgcn_s_setprio(1);
        MFMA16(afa, bfa, 0, 0);
        MFMA16(afa, bfb, 0, 2);
        __builtin_amdgcn_s_setprio(0);
        SBAR();
        // ---- Phase B ----
        STAGE_HALF(4 * t + 8);
        STAGE_HALF(4 * t + 9);
        if (CONV) {
            u32x2 q;
            q[0] = cvtpk(cv[0], cv[1]);
            q[1] = cvtpk(cv[2], cv[3]);
            __builtin_nontemporal_store(q,
                (u32x2*)(cdst + ((size_t)fid * NT + t) * 2048 + tid * 4));
        }
        LOAD_A11(afb, 1);
        __builtin_amdgcn_s_setprio(1);
        MFMA16(afb, bfa, 4, 0);
        MFMA16(afb, bfb, 4, 2);
        __builtin_amdgcn_s_setprio(0);
        if (CONV && t + 1 < NT) cv = cvn;
        if (t < NT - 2) {
            if (CONV) { asm volatile("s_waitcnt vmcnt(6)" ::: "memory"); }
            else      { asm volatile("s_waitcnt vmcnt(4)" ::: "memory"); }
        } else        { asm volatile("s_waitcnt vmcnt(0)" ::: "memory"); }
        SBAR();
    }

    GEMM_EPILOGUE_256
}

// ===== v12: B global->reg (L2-served), A-only LDS, 1 barrier/K-tile ========
// Mechanism: LDS traffic was the saturated pipe (192KB/K-tile/block >= MFMA
// floor). B panel is 2MB and shared by concurrent same-XCD blocks (m-fast
// swizzle) -> serve B fragments straight from L2 into registers, one K-tile
// ahead (double-buffered reg sets via 2x unroll). LDS keeps only A
// (2x32KB double buffer): 128KB/K-tile < 621cyc MFMA floor.
// Ledger (FIFO): per tile T issue [Ast(T+1)x4, Bld(T+1)x8]; end-of-tile
// vmcnt(8) drains exactly Ast(T+1) (B-regs are compiler-tracked deps, their
// auto-waits are non-blocking: issued a full ~4700cyc tile earlier).
// WAR: STAGE_A(T+1) writes lds[(T+1)&1], whose tile-(T-1) readers completed
// before the barrier ending tile T-1. Tail T=NT-1: guards skip issues,
// vmcnt(0).
__global__ __launch_bounds__(512, 2) void kto_logits_lse_v12(
    const unsigned short* __restrict__ Xb, const unsigned short* __restrict__ Wb,
    float2* __restrict__ part)
{
    __shared__ __align__(16) unsigned char lds[65536];   // A only: 2 x 32KB

    const int tid  = threadIdx.x;
    const int lane = tid & 63;
    const int wave = tid >> 6;
    const int wr   = wave >> 2;
    const int wc   = wave & 3;
    const int lrow = lane & 15;
    const int lgrp = lane >> 4;

    const int fid  = blockIdx.y * gridDim.x + blockIdx.x;
    const int swz  = (fid & 7) * 125 + (fid >> 3);
    const int tile_m = (swz & 7) * BM;
    const int tile_n = (swz >> 3) * BN;

    const int scol = ((lane & 7) * 8) ^ ((lane >> 3) << 3);

    f32x4 acc[8][4];
#pragma unroll
    for (int i = 0; i < 8; ++i)
#pragma unroll
        for (int j = 0; j < 4; ++j) acc[i][j] = f32x4{0.f, 0.f, 0.f, 0.f};

#define STAGE_A12(T)                                                          \
    do { int ta_ = (T);                                                       \
        if (ta_ < NT) {                                                       \
            unsigned char* la_ = lds + (ta_ & 1) * 32768;                     \
            _Pragma("unroll")                                                 \
            for (int h_ = 0; h_ < 2; ++h_)                                    \
            _Pragma("unroll")                                                 \
            for (int c_ = 0; c_ < 2; ++c_) {                                  \
                int rt_ = h_ * 128 + wave * 16 + c_ * 8;                      \
                gload_lds16(Xb + (size_t)(tile_m + rt_ + (lane >> 3)) * HH    \
                               + ta_ * 64 + scol,                             \
                            la_ + rt_ * 128);                                 \
            }                                                                 \
        } } while (0)

// B fragments straight from global (row-major Wb), same logical elements as
// the verified LDS read: row = tile_n + wc*64 + NH*32 + n*16 + lrow,
// elems [t*64 + kk*32 + lgrp*8, +8).
#define BLOAD12(B0, B1, T)                                                    \
    do { int tb_ = (T);                                                       \
        if (tb_ < NT) {                                                       \
            _Pragma("unroll")                                                 \
            for (int n_ = 0; n_ < 2; ++n_)                                    \
            _Pragma("unroll")                                                 \
            for (int kk_ = 0; kk_ < 2; ++kk_) {                               \
                B0[n_][kk_] = *(const short8*)(Wb +                           \
                    (size_t)(tile_n + wc * 64 + n_ * 16 + lrow) * HH          \
                    + tb_ * 64 + kk_ * 32 + lgrp * 8);                        \
                B1[n_][kk_] = *(const short8*)(Wb +                           \
                    (size_t)(tile_n + wc * 64 + 32 + n_ * 16 + lrow) * HH     \
                    + tb_ * 64 + kk_ * 32 + lgrp * 8);                        \
            }                                                                 \
        } } while (0)

#define LOAD_A12(DST, MH)                                                     \
    _Pragma("unroll") for (int m_ = 0; m_ < 4; ++m_)                          \
    _Pragma("unroll") for (int kk_ = 0; kk_ < 2; ++kk_) {                     \
        int rr_ = wr * 128 + (MH) * 64 + m_ * 16 + lrow;                      \
        DST[m_][kk_] = *(const short8*)(ldsAp + rr_ * 128 +                   \
            ((kk_ * 64 + lgrp * 16) ^ ((rr_ & 7) << 4))); }

#define TILE12(T, BU0, BU1, BF0, BF1)                                         \
    do {                                                                      \
        const unsigned char* ldsAp = lds + ((T) & 1) * 32768;                 \
        short8 afa[4][2], afb[4][2];                                          \
        STAGE_A12((T) + 1);                                                   \
        BLOAD12(BF0, BF1, (T) + 1);                                           \
        LOAD_A12(afa, 0);                                                     \
        LOAD_A12(afb, 1);                                                     \
        __builtin_amdgcn_s_setprio(1);                                        \
        MFMA16(afa, BU0, 0, 0);                                               \
        MFMA16(afa, BU1, 0, 2);                                               \
        MFMA16(afb, BU0, 4, 0);                                               \
        MFMA16(afb, BU1, 4, 2);                                               \
        __builtin_amdgcn_s_setprio(0);                                        \
        if ((T) < NT - 1) { asm volatile("s_waitcnt vmcnt(8)" ::: "memory"); }\
        else              { asm volatile("s_waitcnt vmcnt(0)" ::: "memory"); }\
        SBAR();                                                               \
    } while (0)

    short8 bA0[2][2], bA1[2][2], bB0[2][2], bB1[2][2];

    // Prologue: A(0) staged, B(0) in flight to regs.
    STAGE_A12(0);
    BLOAD12(bA0, bA1, 0);
    asm volatile("s_waitcnt vmcnt(8)" ::: "memory");   // drain Ast(0)x4
    SBAR();

    for (int t = 0; t < NT; t += 2) {
        TILE12(t,     bA0, bA1, bB0, bB1);
        TILE12(t + 1, bB0, bB1, bA0, bA1);
    }

    GEMM_EPILOGUE_256
}

// ---------------- fallback: round-1 fused fp32 reg-staged GEMM (128²) -------
__global__ __launch_bounds__(256) void kto_logits_lse(
    const float* __restrict__ X, const float* __restrict__ Wt,
    float2* __restrict__ part)
{
    __shared__ __align__(16) unsigned char ldsf[(128 + 128) * BK * 2];
    unsigned char* ldsA = ldsf;
    unsigned char* ldsB = ldsf + 128 * BK * 2;

    const int tid    = threadIdx.x;
    const int tile_m = blockIdx.x * 128;
    const int tile_n = blockIdx.y * 128;
    const int srow   = tid >> 1;
    const int shalf  = tid & 1;
    const int lane   = tid & 63;
    const int wave   = tid >> 6;
    const int wm     = (wave >> 1) * 64;
    const int wn     = (wave & 1) * 64;
    const int lrow   = lane & 15;
    const int lgrp   = lane >> 4;

    f32x4 acc[4][4];
#pragma unroll
    for (int i = 0; i < 4; ++i)
#pragma unroll
        for (int j = 0; j < 4; ++j) acc[i][j] = f32x4{0.f, 0.f, 0.f, 0.f};

    const float4* gA = (const float4*)(X  + (size_t)(tile_m + srow) * HH) + shalf * 8;
    const float4* gB = (const float4*)(Wt + (size_t)(tile_n + srow) * HH) + shalf * 8;
    const int swzf = (srow & 7) << 4;

    for (int k0 = 0; k0 < HH; k0 += BK) {
        float4 a[8], b[8];
#pragma unroll
        for (int j = 0; j < 8; ++j) a[j] = gA[j];
#pragma unroll
        for (int j = 0; j < 8; ++j) b[j] = gB[j];
        gA += BK / 4; gB += BK / 4;

        __syncthreads();
#pragma unroll
        for (int j = 0; j < 4; ++j) {
            uint2 lo = pack4(a[2*j]), hi = pack4(a[2*j+1]);
            uint4 qa = make_uint4(lo.x, lo.y, hi.x, hi.y);
            lo = pack4(b[2*j]); hi = pack4(b[2*j+1]);
            uint4 qb = make_uint4(lo.x, lo.y, hi.x, hi.y);
            int kb = shalf * 64 + 16 * j;
            *(uint4*)(ldsA + srow * 128 + (kb ^ swzf)) = qa;
            *(uint4*)(ldsB + srow * 128 + (kb ^ swzf)) = qb;
        }
        __syncthreads();

#pragma unroll
        for (int kk = 0; kk < 2; ++kk) {
            short8 af[4], bf[4];
#pragma unroll
            for (int mi = 0; mi < 4; ++mi) {
                int r = wm + mi * 16 + lrow;
                af[mi] = *(const short8*)(ldsA + r * 128 + ((kk * 64 + lgrp * 16) ^ ((r & 7) << 4)));
            }
#pragma unroll
            for (int ni = 0; ni < 4; ++ni) {
                int r = wn + ni * 16 + lrow;
                bf[ni] = *(const short8*)(ldsB + r * 128 + ((kk * 64 + lgrp * 16) ^ ((r & 7) << 4)));
            }
#pragma unroll
            for (int mi = 0; mi < 4; ++mi)
#pragma unroll
                for (int ni = 0; ni < 4; ++ni)
                    acc[mi][ni] = __builtin_amdgcn_mfma_f32_16x16x32_bf16(af[mi], bf[ni], acc[mi][ni], 0, 0, 0);
        }
    }

    const int nbf = blockIdx.y * 2 + (wave & 1);
#pragma unroll
    for (int mi = 0; mi < 4; ++mi) {
#pragma unroll
        for (int r = 0; r < 4; ++r) {
            float v0 = acc[mi][0][r], v1 = acc[mi][1][r], v2 = acc[mi][2][r], v3 = acc[mi][3][r];
            float mx = fmaxf(fmaxf(v0, v1), fmaxf(v2, v3));
#pragma unroll
            for (int d = 1; d < 16; d <<= 1) mx = fmaxf(mx, __shfl_xor(mx, d, 64));
            float s = __expf(v0 - mx) + __expf(v1 - mx) + __expf(v2 - mx) + __expf(v3 - mx);
#pragma unroll
            for (int d = 1; d < 16; d <<= 1) s += __shfl_xor(s, d, 64);
            if (lrow == 0) {
                int rowg = tile_m + wm + mi * 16 + lgrp * 4 + r;
                part[(size_t)rowg * NPB + nbf] = make_float2(mx, s);
            }
        }
    }
}

// ---------------- target logit per token (fp32 exact) -----------------------
__global__ __launch_bounds__(256) void kto_target(
    const float* __restrict__ X, const float* __restrict__ RX,
    const float* __restrict__ W, const float* __restrict__ RW,
    const int* __restrict__ Y,
    float* __restrict__ tgtP, float* __restrict__ tgtR)
{
    __shared__ float red[2][4];
    const int t = blockIdx.x;
    int yt = Y[t]; yt = yt < 0 ? 0 : (yt > VV - 1 ? VV - 1 : yt);
    const float4* x4  = (const float4*)(X  + (size_t)t  * HH);
    const float4* rx4 = (const float4*)(RX + (size_t)t  * HH);
    const float4* w4  = (const float4*)(W  + (size_t)yt * HH);
    const float4* rw4 = (const float4*)(RW + (size_t)yt * HH);
    float sp = 0.f, sr = 0.f;
    for (int i = threadIdx.x; i < HH / 4; i += 256) {
        float4 a = x4[i],  w = w4[i];
        sp += a.x * w.x + a.y * w.y + a.z * w.z + a.w * w.w;
        float4 bq = rx4[i], rw = rw4[i];
        sr += bq.x * rw.x + bq.y * rw.y + bq.z * rw.z + bq.w * rw.w;
    }
#pragma unroll
    for (int d = 1; d < 64; d <<= 1) { sp += __shfl_xor(sp, d, 64); sr += __shfl_xor(sr, d, 64); }
    int wv = threadIdx.x >> 6, ln = threadIdx.x & 63;
    if (ln == 0) { red[0][wv] = sp; red[1][wv] = sr; }
    __syncthreads();
    if (threadIdx.x == 0) {
        tgtP[t] = red[0][0] + red[0][1] + red[0][2] + red[0][3];
        tgtR[t] = red[1][0] + red[1][1] + red[1][2] + red[1][3];
    }
}

__device__ inline float2 mrg(float2 a, float2 b) {
    if (b.x == -INFINITY) return a;
    if (a.x == -INFINITY) return b;
    if (a.x >= b.x) { a.y += b.y * __expf(b.x - a.x); return a; }
    b.y += a.y * __expf(a.x - b.x); return b;
}

__global__ __launch_bounds__(256) void kto_lse_combine(
    const float2* __restrict__ partP, const float2* __restrict__ partR,
    const float* __restrict__ tgtP, const float* __restrict__ tgtR,
    float* __restrict__ tokP, float* __restrict__ tokR)
{
    __shared__ float2 redP[4], redR[4];
    const int t = blockIdx.x;
    float2 ap = make_float2(-INFINITY, 0.f), ar = ap;
    for (int i = threadIdx.x; i < NPB; i += 256) {
        ap = mrg(ap, partP[(size_t)t * NPB + i]);
        ar = mrg(ar, partR[(size_t)t * NPB + i]);
    }
#pragma unroll
    for (int d = 1; d < 64; d <<= 1) {
        float2 o;
        o.x = __shfl_xor(ap.x, d, 64); o.y = __shfl_xor(ap.y, d, 64); ap = mrg(ap, o);
        o.x = __shfl_xor(ar.x, d, 64); o.y = __shfl_xor(ar.y, d, 64); ar = mrg(ar, o);
    }
    int wv = threadIdx.x >> 6, ln = threadIdx.x & 63;
    if (ln == 0) { redP[wv] = ap; redR[wv] = ar; }
    __syncthreads();
    if (threadIdx.x == 0) {
        float2 p = mrg(mrg(redP[0], redP[1]), mrg(redP[2], redP[3]));
        float2 r = mrg(mrg(redR[0], redR[1]), mrg(redR[2], redR[3]));
        tokP[t] = tgtP[t] - (p.x + logf(p.y));
        tokR[t] = tgtR[t] - (r.x + logf(r.y));
    }
}

__global__ __launch_bounds__(1024) void kto_final(
    const float* __restrict__ tokP, const float* __restrict__ tokR,
    const int* __restrict__ Y, const unsigned char* __restrict__ pref,
    float* __restrict__ out)
{
    __shared__ float red[6][16];
    const int t = threadIdx.x;  // 0..1023
    float m0 = (Y[t]      != -100) ? 1.f : 0.f;
    float m1 = (Y[TT + t] != -100) ? 1.f : 0.f;
    float v[6];
    v[0] = m0 * tokP[t];       v[1] = m0 * tokR[t];       v[2] = m0;
    v[3] = m1 * tokP[TT + t];  v[4] = m1 * tokR[TT + t];  v[5] = m1;
#pragma unroll
    for (int d = 1; d < 64; d <<= 1)
#pragma unroll
        for (int j = 0; j < 6; ++j) v[j] += __shfl_xor(v[j], d, 64);
    int wv = threadIdx.x >> 6, ln = threadIdx.x & 63;
    if (ln == 0)
#pragma unroll
        for (int j = 0; j < 6; ++j) red[j][wv] = v[j];
    __syncthreads();
    if (t == 0) {
        float s[6];
#pragma unroll
        for (int j = 0; j < 6; ++j) { s[j] = 0.f; for (int w = 0; w < 16; ++w) s[j] += red[j][w]; }
        bool byteStorage = ((pref[1] | pref[2] | pref[3]) != 0) || (pref[4] > 1) ||
                           ((pref[5] | pref[6] | pref[7]) != 0);
        int l0, l1;
        if (byteStorage) { l0 = pref[0]; l1 = pref[1]; }
        else { l0 = ((const int*)pref)[0]; l1 = ((const int*)pref)[1]; }
        float pl0 = s[0] / fmaxf(s[2], 1.f);
        float rl0 = s[1] / fmaxf(s[2], 1.f);
        float pl1 = s[3] / fmaxf(s[5], 1.f);
        float rl1 = s[4] / fmaxf(s[5], 1.f);
        float lr0 = pl0 - rl0, lr1 = pl1 - rl1;
        float mu0 = l0 ? 1.f : -1.f;
        float mu1 = l1 ? 1.f : -1.f;
        float loss0 = 1.f - 1.f / (1.f + expf(-BETA_ * lr0 * mu0));
        float loss1 = 1.f - 1.f / (1.f + expf(-BETA_ * lr1 * mu1));
        out[0] = 0.5f * (loss0 + loss1);
    }
}

extern "C" void kernel_launch(void* const* d_in, const int* in_sizes, int n_in,
                              void* d_out, int out_size, void* d_ws, size_t ws_size,
                              hipStream_t stream) {
    const float* X  = (const float*)d_in[0];
    const float* RX = (const float*)d_in[1];
    const int*   Y  = (const int*)d_in[2];
    const unsigned char* PL = (const unsigned char*)d_in[3];
    const float* W  = (const float*)d_in[4];
    const float* RW = (const float*)d_in[5];
    float* out = (float*)d_out;

    // ws layout
    char* p = (char*)d_ws;
    float2* partP = (float2*)p;                 p += (size_t)MM * NPB * sizeof(float2);
    float2* partR = (float2*)p;                 p += (size_t)MM * NPB * sizeof(float2);
    float*  tgtP  = (float*)p;                  p += MM * sizeof(float);
    float*  tgtR  = (float*)p;                  p += MM * sizeof(float);
    float*  tokP  = (float*)p;                  p += MM * sizeof(float);
    float*  tokR  = (float*)p;                  p += MM * sizeof(float);
    unsigned short* Xbf  = (unsigned short*)p;  p += (size_t)MM * HH * 2;
    unsigned short* RXbf = (unsigned short*)p;  p += (size_t)MM * HH * 2;
    unsigned short* Wbf  = (unsigned short*)p;  p += (size_t)VV * HH * 2;
    const size_t need1 = (size_t)(p - (char*)d_ws);           // round-6 tier
    unsigned short* RWbf = (unsigned short*)p;  p += (size_t)VV * HH * 2;
    const size_t need2 = (size_t)(p - (char*)d_ws);           // fused tier

    dim3 ggrid(MM / BM, VV / BN);  // (8, 125)

    if (ws_size >= need2) {
        // tier 1: conv X/RX/W; GEMM-1 = v11<true> (banked side-convert of RW);
        // GEMM-2 = v12 (B from L2 to regs, A-only LDS, 1 barrier/K-tile).
        conv_bf16<<<512,  256, 0, stream>>>(X,  Xbf,  (int)((size_t)MM * HH / 8));
        conv_bf16<<<512,  256, 0, stream>>>(RX, RXbf, (int)((size_t)MM * HH / 8));
        conv_bf16<<<2048, 256, 0, stream>>>(W,  Wbf,  (int)((size_t)VV * HH / 8));
        kto_logits_lse_v11<true><<<ggrid, 512, 0, stream>>>(Xbf, Wbf, partP, RW, RWbf);
        kto_logits_lse_v12<<<ggrid, 512, 0, stream>>>(RXbf, RWbf, partR);
    } else if (ws_size >= need1) {
        // tier 2: serial RW conversion into Wbf, v12 GEMMs.
        conv_bf16<<<512,  256, 0, stream>>>(X,  Xbf,  (int)((size_t)MM * HH / 8));
        conv_bf16<<<512,  256, 0, stream>>>(RX, RXbf, (int)((size_t)MM * HH / 8));
        conv_bf16<<<2048, 256, 0, stream>>>(W,  Wbf,  (int)((size_t)VV * HH / 8));
        kto_logits_lse_v12<<<ggrid, 512, 0, stream>>>(Xbf, Wbf, partP);
        conv_bf16<<<2048, 256, 0, stream>>>(RW, Wbf,  (int)((size_t)VV * HH / 8));
        kto_logits_lse_v12<<<ggrid, 512, 0, stream>>>(RXbf, Wbf, partR);
    } else {
        // tier 3: fused fp32 reg-staged path (round-1, known-correct)
        dim3 fgrid(MM / 128, VV / 128);
        kto_logits_lse<<<fgrid, 256, 0, stream>>>(X,  W,  partP);
        kto_logits_lse<<<fgrid, 256, 0, stream>>>(RX, RW, partR);
    }
    kto_target<<<MM, 256, 0, stream>>>(X, RX, W, RW, Y, tgtP, tgtR);
    kto_lse_combine<<<MM, 256, 0, stream>>>(partP, partR, tgtP, tgtR, tokP, tokR);
    kto_final<<<1, 1024, 0, stream>>>(tokP, tokR, Y, PL, out);
}

// Round 14
// 1163.170 us; speedup vs baseline: 2.3952x; 2.3952x over previous
//
#include <hip/hip_runtime.h>
#include <hip/hip_bf16.h>
#include <math.h>

// Problem constants (B,T,H,V) = (2,1024,4096,32000)
#define TT 1024
#define MM 2048      // B*T tokens
#define HH 4096
#define VV 32000
#define BETA_ 0.1f
#define NPB (VV/64)  // 500 partial (max,sumexp) blocks per token row

// GEMM geometry
#define BM 256
#define BN 256
#define BK 64
#define NT (HH/BK)   // 64 K-tiles

typedef short short8 __attribute__((ext_vector_type(8)));
typedef float f32x4 __attribute__((ext_vector_type(4)));
typedef unsigned u32x2 __attribute__((ext_vector_type(2)));

__device__ inline unsigned f2bf1(float f) {
    union { float f; unsigned u; } v; v.f = f;
    return (v.u + 0x7fffu + ((v.u >> 16) & 1u)) >> 16;   // RNE f32->bf16
}
__device__ inline uint2 pack4(float4 a) {
    uint2 r;
    r.x = f2bf1(a.x) | (f2bf1(a.y) << 16);
    r.y = f2bf1(a.z) | (f2bf1(a.w) << 16);
    return r;
}
// RNE pack via v_cvt_pk_bf16_f32 (identical rounding to f2bf1).
__device__ inline unsigned cvtpk(float lo, float hi) {
    union { __hip_bfloat162 h; unsigned u; } v;
    v.h = __float22bfloat162_rn(make_float2(lo, hi));
    return v.u;
}

// global -> LDS direct copy, 16B per lane. LDS dest is wave-uniform base + lane*16.
__device__ __forceinline__ void gload_lds16(const void* g, void* l) {
    __builtin_amdgcn_global_load_lds(
        (const __attribute__((address_space(1))) void*)(uintptr_t)g,
        (__attribute__((address_space(3))) void*)(unsigned)(uintptr_t)l,
        16, 0, 0);
}

// ---------------- fp32 -> bf16 pre-conversion (8 elem / thread / iter) ------
__global__ __launch_bounds__(256) void conv_bf16(
    const float* __restrict__ src, unsigned short* __restrict__ dst, int n8)
{
    int i = blockIdx.x * 256 + threadIdx.x;
    const int stride = gridDim.x * 256;
    for (; i < n8; i += stride) {
        const float4* s = (const float4*)src + 2 * (size_t)i;
        float4 a = s[0], b = s[1];
        uint2 lo = pack4(a), hi = pack4(b);
        *(uint4*)(dst + (size_t)i * 8) = make_uint4(lo.x, lo.y, hi.x, hi.y);
    }
}

// ===== v11: round-6 2-phase GEMM (2 barriers/K-tile, counted vmcnt) ========
// CONV=true additionally stream-converts RW fp32 -> RWbf bf16 (the OTHER
// GEMM's operand) using spare HBM BW:
//  (1) cvLd issued AFTER the A-stages (vmcnt retires in issue order, so the
//      cold cvLd is never drained by the per-tile counted wait);
//  (2) nontemporal load/store for the conv stream (L2 pollution);
//  (3) 2-phase consumption lead via cv/cvn register rotate.
// Ledger (FIFO, steady state at phase-B(t) end, before wait):
//   [A-st(t+1)x4, cvLd(t+1), B-st(t+2)x4, St(t)] = 10
//   vmcnt(6): drains exactly A(t+1)x4; leaves [cvLd(t+1), B(t+2)x4, St(t)]=6.
//   cv rotate (cv=cvn) auto-waits cvLd(t+1), issued ~2600 cyc earlier.
//   Prologue: 12 stage loads + cvLd(0) = 13; vmcnt(5) retires tile-0's 8.
//   Tail t>=NT-2: guards shrink the queue -> vmcnt(0).
// CONV=false is round-6 v6 exactly (vmcnt(4)). Measured (round 12):
// CONV-GEMM 567-585us, non-CONV ~488us, end-to-end 1166us.
template<bool CONV>
__global__ __launch_bounds__(512, 2) void kto_logits_lse_v11(
    const unsigned short* __restrict__ Xb, const unsigned short* __restrict__ Wb,
    float2* __restrict__ part,
    const float* __restrict__ csrc, unsigned short* __restrict__ cdst)
{
    __shared__ __align__(16) unsigned char lds[131072];  // A: 2x32KB | B: 2x32KB

    const int tid  = threadIdx.x;
    const int lane = tid & 63;
    const int wave = tid >> 6;        // 0..7
    const int wr   = wave >> 2;       // 0..1  (M)
    const int wc   = wave & 3;        // 0..3  (N)
    const int lrow = lane & 15;
    const int lgrp = lane >> 4;

    // XCD-aware bijective swizzle: 1000 wgs, 8 XCDs, chunks of 125, m-fast.
    const int fid  = blockIdx.y * gridDim.x + blockIdx.x;   // 0..999
    const int swz  = (fid & 7) * 125 + (fid >> 3);
    const int tile_m = (swz & 7) * BM;     // 8 m-tiles
    const int tile_n = (swz >> 3) * BN;    // 125 n-tiles

    // Pre-swizzled staging source column (elements); matches ds_read XOR.
    const int scol = ((lane & 7) * 8) ^ ((lane >> 3) << 3);

    f32x4 acc[8][4];
#pragma unroll
    for (int i = 0; i < 8; ++i)
#pragma unroll
        for (int j = 0; j < 4; ++j) acc[i][j] = f32x4{0.f, 0.f, 0.f, 0.f};

#define STAGE_HALF(S)                                                         \
    do { int s_ = (S);                                                        \
        if (s_ < 4 * NT) {                                                    \
            int ts_ = s_ >> 2, kind_ = s_ & 3, buf_ = ts_ & 1;                \
            int isA_ = kind_ >> 1, half_ = kind_ & 1;                         \
            const unsigned short* base_ = isA_                                \
                ? Xb + (size_t)tile_m * HH : Wb + (size_t)tile_n * HH;        \
            unsigned char* lb_ = lds + (isA_ ? 0 : 65536) + buf_ * 32768;     \
            _Pragma("unroll")                                                 \
            for (int c_ = 0; c_ < 2; ++c_) {                                  \
                int rt_ = half_ * 128 + wave * 16 + c_ * 8;                   \
                gload_lds16(base_ + (size_t)(rt_ + (lane >> 3)) * HH          \
                                  + ts_ * 64 + scol,                          \
                            lb_ + rt_ * 128);                                 \
            }                                                                 \
        } } while (0)

#define LOAD_A(DST, MH)                                                       \
    _Pragma("unroll") for (int m_ = 0; m_ < 4; ++m_)                          \
    _Pragma("unroll") for (int kk_ = 0; kk_ < 2; ++kk_) {                     \
        int rr_ = wr * 128 + (MH) * 64 + m_ * 16 + lrow;                      \
        DST[m_][kk_] = *(const short8*)(ldsAp + rr_ * 128 +                   \
            ((kk_ * 64 + lgrp * 16) ^ ((rr_ & 7) << 4))); }

#define LOAD_B(DST, NH)                                                       \
    _Pragma("unroll") for (int n_ = 0; n_ < 2; ++n_)                          \
    _Pragma("unroll") for (int kk_ = 0; kk_ < 2; ++kk_) {                     \
        int rb_ = wc * 64 + (NH) * 32 + n_ * 16 + lrow;                       \
        DST[n_][kk_] = *(const short8*)(ldsBp + rb_ * 128 +                   \
            ((kk_ * 64 + lgrp * 16) ^ ((rb_ & 7) << 4))); }

#define MFMA16(AF, BF, MB, NB)                                                \
    _Pragma("unroll") for (int m_ = 0; m_ < 4; ++m_)                          \
    _Pragma("unroll") for (int n_ = 0; n_ < 2; ++n_)                          \
    _Pragma("unroll") for (int kk_ = 0; kk_ < 2; ++kk_)                       \
        acc[(MB) + m_][(NB) + n_] = __builtin_amdgcn_mfma_f32_16x16x32_bf16(  \
            AF[m_][kk_], BF[n_][kk_], acc[(MB) + m_][(NB) + n_], 0, 0, 0);

#define SBAR()                                                                \
    __builtin_amdgcn_sched_barrier(0);                                        \
    __builtin_amdgcn_s_barrier();                                             \
    __builtin_amdgcn_sched_barrier(0);

    f32x4 cv, cvn;

    // Prologue: stage halves 0..5 (12 loads), then cvLd(0) (youngest);
    // vmcnt(5) retires tile-0's 8 loads, leaves [B(1)x4, cvLd(0)].
#pragma unroll
    for (int s = 0; s < 6; ++s) STAGE_HALF(s);
    if (CONV) {
        cv = __builtin_nontemporal_load(
            (const f32x4*)(csrc + (size_t)fid * NT * 2048 + tid * 4));
        asm volatile("s_waitcnt vmcnt(5)" ::: "memory");
    } else {
        asm volatile("s_waitcnt vmcnt(4)" ::: "memory");
    }
    SBAR();

    for (int t = 0; t < NT; ++t) {
        const int p = t & 1;
        const unsigned char* ldsAp = lds + p * 32768;
        const unsigned char* ldsBp = lds + 65536 + p * 32768;
        short8 afa[4][2], afb[4][2], bfa[2][2], bfb[2][2];

        // ---- Phase A ----
        STAGE_HALF(4 * t + 6);
        STAGE_HALF(4 * t + 7);
        if (CONV && t + 1 < NT)     // cvLd AFTER the A-stages: never on the
            cvn = __builtin_nontemporal_load(   // counted-wait critical path
                (const f32x4*)(csrc + ((size_t)fid * NT + t + 1) * 2048 + tid * 4));
        LOAD_A(afa, 0);
        LOAD_B(bfa, 0);
        LOAD_B(bfb, 1);
        __builtin_amdgcn_s_setprio(1);
        MFMA16(afa, bfa, 0, 0);
        MFMA16(afa, bfb, 0, 2);
        __builtin_amdgcn_s_setprio(0);
        SBAR();
        // ---- Phase B ----
        STAGE_HALF(4 * t + 8);
        STAGE_HALF(4 * t + 9);
        if (CONV) {
            // cv loaded 2 phases ago; pack free, store youngest in FIFO.
            u32x2 q;
            q[0] = cvtpk(cv[0], cv[1]);
            q[1] = cvtpk(cv[2], cv[3]);
            __builtin_nontemporal_store(q,
                (u32x2*)(cdst + ((size_t)fid * NT + t) * 2048 + tid * 4));
        }
        LOAD_A(afb, 1);
        __builtin_amdgcn_s_setprio(1);
        MFMA16(afb, bfa, 4, 0);
        MFMA16(afb, bfb, 4, 2);
        __builtin_amdgcn_s_setprio(0);
        if (CONV && t + 1 < NT) cv = cvn;   // rotate; auto-wait drains cvLd
        if (t < NT - 2) {
            if (CONV) { asm volatile("s_waitcnt vmcnt(6)" ::: "memory"); }
            else      { asm volatile("s_waitcnt vmcnt(4)" ::: "memory"); }
        } else        { asm volatile("s_waitcnt vmcnt(0)" ::: "memory"); }
        SBAR();
    }

    // Epilogue: per token row, (max, sumexp) over this wave's 64 vocab cols.
    // C/D layout: col = lane&15, row = (lane>>4)*4 + reg  [m89/m91]
    const int nb = (tile_n >> 6) + wc;
#pragma unroll
    for (int mi = 0; mi < 8; ++mi) {
#pragma unroll
        for (int r = 0; r < 4; ++r) {
            float v0 = acc[mi][0][r], v1 = acc[mi][1][r], v2 = acc[mi][2][r], v3 = acc[mi][3][r];
            float mx = fmaxf(fmaxf(v0, v1), fmaxf(v2, v3));
#pragma unroll
            for (int d = 1; d < 16; d <<= 1) mx = fmaxf(mx, __shfl_xor(mx, d, 64));
            float s = __expf(v0 - mx) + __expf(v1 - mx) + __expf(v2 - mx) + __expf(v3 - mx);
#pragma unroll
            for (int d = 1; d < 16; d <<= 1) s += __shfl_xor(s, d, 64);
            if (lrow == 0) {
                int rowg = tile_m + wr * 128 + mi * 16 + lgrp * 4 + r;
                part[(size_t)rowg * NPB + nb] = make_float2(mx, s);
            }
        }
    }
}

// ---------------- fallback: round-1 fused fp32 reg-staged GEMM (128²) -------
__global__ __launch_bounds__(256) void kto_logits_lse(
    const float* __restrict__ X, const float* __restrict__ Wt,
    float2* __restrict__ part)
{
    __shared__ __align__(16) unsigned char ldsf[(128 + 128) * BK * 2];
    unsigned char* ldsA = ldsf;
    unsigned char* ldsB = ldsf + 128 * BK * 2;

    const int tid    = threadIdx.x;
    const int tile_m = blockIdx.x * 128;
    const int tile_n = blockIdx.y * 128;
    const int srow   = tid >> 1;
    const int shalf  = tid & 1;
    const int lane   = tid & 63;
    const int wave   = tid >> 6;
    const int wm     = (wave >> 1) * 64;
    const int wn     = (wave & 1) * 64;
    const int lrow   = lane & 15;
    const int lgrp   = lane >> 4;

    f32x4 acc[4][4];
#pragma unroll
    for (int i = 0; i < 4; ++i)
#pragma unroll
        for (int j = 0; j < 4; ++j) acc[i][j] = f32x4{0.f, 0.f, 0.f, 0.f};

    const float4* gA = (const float4*)(X  + (size_t)(tile_m + srow) * HH) + shalf * 8;
    const float4* gB = (const float4*)(Wt + (size_t)(tile_n + srow) * HH) + shalf * 8;
    const int swzf = (srow & 7) << 4;

    for (int k0 = 0; k0 < HH; k0 += BK) {
        float4 a[8], b[8];
#pragma unroll
        for (int j = 0; j < 8; ++j) a[j] = gA[j];
#pragma unroll
        for (int j = 0; j < 8; ++j) b[j] = gB[j];
        gA += BK / 4; gB += BK / 4;

        __syncthreads();
#pragma unroll
        for (int j = 0; j < 4; ++j) {
            uint2 lo = pack4(a[2*j]), hi = pack4(a[2*j+1]);
            uint4 qa = make_uint4(lo.x, lo.y, hi.x, hi.y);
            lo = pack4(b[2*j]); hi = pack4(b[2*j+1]);
            uint4 qb = make_uint4(lo.x, lo.y, hi.x, hi.y);
            int kb = shalf * 64 + 16 * j;
            *(uint4*)(ldsA + srow * 128 + (kb ^ swzf)) = qa;
            *(uint4*)(ldsB + srow * 128 + (kb ^ swzf)) = qb;
        }
        __syncthreads();

#pragma unroll
        for (int kk = 0; kk < 2; ++kk) {
            short8 af[4], bf[4];
#pragma unroll
            for (int mi = 0; mi < 4; ++mi) {
                int r = wm + mi * 16 + lrow;
                af[mi] = *(const short8*)(ldsA + r * 128 + ((kk * 64 + lgrp * 16) ^ ((r & 7) << 4)));
            }
#pragma unroll
            for (int ni = 0; ni < 4; ++ni) {
                int r = wn + ni * 16 + lrow;
                bf[ni] = *(const short8*)(ldsB + r * 128 + ((kk * 64 + lgrp * 16) ^ ((r & 7) << 4)));
            }
#pragma unroll
            for (int mi = 0; mi < 4; ++mi)
#pragma unroll
                for (int ni = 0; ni < 4; ++ni)
                    acc[mi][ni] = __builtin_amdgcn_mfma_f32_16x16x32_bf16(af[mi], bf[ni], acc[mi][ni], 0, 0, 0);
        }
    }

    const int nbf = blockIdx.y * 2 + (wave & 1);
#pragma unroll
    for (int mi = 0; mi < 4; ++mi) {
#pragma unroll
        for (int r = 0; r < 4; ++r) {
            float v0 = acc[mi][0][r], v1 = acc[mi][1][r], v2 = acc[mi][2][r], v3 = acc[mi][3][r];
            float mx = fmaxf(fmaxf(v0, v1), fmaxf(v2, v3));
#pragma unroll
            for (int d = 1; d < 16; d <<= 1) mx = fmaxf(mx, __shfl_xor(mx, d, 64));
            float s = __expf(v0 - mx) + __expf(v1 - mx) + __expf(v2 - mx) + __expf(v3 - mx);
#pragma unroll
            for (int d = 1; d < 16; d <<= 1) s += __shfl_xor(s, d, 64);
            if (lrow == 0) {
                int rowg = tile_m + wm + mi * 16 + lgrp * 4 + r;
                part[(size_t)rowg * NPB + nbf] = make_float2(mx, s);
            }
        }
    }
}

// ---------------- target logit per token (fp32 exact) -----------------------
__global__ __launch_bounds__(256) void kto_target(
    const float* __restrict__ X, const float* __restrict__ RX,
    const float* __restrict__ W, const float* __restrict__ RW,
    const int* __restrict__ Y,
    float* __restrict__ tgtP, float* __restrict__ tgtR)
{
    __shared__ float red[2][4];
    const int t = blockIdx.x;
    int yt = Y[t]; yt = yt < 0 ? 0 : (yt > VV - 1 ? VV - 1 : yt);
    const float4* x4  = (const float4*)(X  + (size_t)t  * HH);
    const float4* rx4 = (const float4*)(RX + (size_t)t  * HH);
    const float4* w4  = (const float4*)(W  + (size_t)yt * HH);
    const float4* rw4 = (const float4*)(RW + (size_t)yt * HH);
    float sp = 0.f, sr = 0.f;
    for (int i = threadIdx.x; i < HH / 4; i += 256) {
        float4 a = x4[i],  w = w4[i];
        sp += a.x * w.x + a.y * w.y + a.z * w.z + a.w * w.w;
        float4 bq = rx4[i], rw = rw4[i];
        sr += bq.x * rw.x + bq.y * rw.y + bq.z * rw.z + bq.w * rw.w;
    }
#pragma unroll
    for (int d = 1; d < 64; d <<= 1) { sp += __shfl_xor(sp, d, 64); sr += __shfl_xor(sr, d, 64); }
    int wv = threadIdx.x >> 6, ln = threadIdx.x & 63;
    if (ln == 0) { red[0][wv] = sp; red[1][wv] = sr; }
    __syncthreads();
    if (threadIdx.x == 0) {
        tgtP[t] = red[0][0] + red[0][1] + red[0][2] + red[0][3];
        tgtR[t] = red[1][0] + red[1][1] + red[1][2] + red[1][3];
    }
}

__device__ inline float2 mrg(float2 a, float2 b) {
    if (b.x == -INFINITY) return a;
    if (a.x == -INFINITY) return b;
    if (a.x >= b.x) { a.y += b.y * __expf(b.x - a.x); return a; }
    b.y += a.y * __expf(a.x - b.x); return b;
}

__global__ __launch_bounds__(256) void kto_lse_combine(
    const float2* __restrict__ partP, const float2* __restrict__ partR,
    const float* __restrict__ tgtP, const float* __restrict__ tgtR,
    float* __restrict__ tokP, float* __restrict__ tokR)
{
    __shared__ float2 redP[4], redR[4];
    const int t = blockIdx.x;
    float2 ap = make_float2(-INFINITY, 0.f), ar = ap;
    for (int i = threadIdx.x; i < NPB; i += 256) {
        ap = mrg(ap, partP[(size_t)t * NPB + i]);
        ar = mrg(ar, partR[(size_t)t * NPB + i]);
    }
#pragma unroll
    for (int d = 1; d < 64; d <<= 1) {
        float2 o;
        o.x = __shfl_xor(ap.x, d, 64); o.y = __shfl_xor(ap.y, d, 64); ap = mrg(ap, o);
        o.x = __shfl_xor(ar.x, d, 64); o.y = __shfl_xor(ar.y, d, 64); ar = mrg(ar, o);
    }
    int wv = threadIdx.x >> 6, ln = threadIdx.x & 63;
    if (ln == 0) { redP[wv] = ap; redR[wv] = ar; }
    __syncthreads();
    if (threadIdx.x == 0) {
        float2 p = mrg(mrg(redP[0], redP[1]), mrg(redP[2], redP[3]));
        float2 r = mrg(mrg(redR[0], redR[1]), mrg(redR[2], redR[3]));
        tokP[t] = tgtP[t] - (p.x + logf(p.y));
        tokR[t] = tgtR[t] - (r.x + logf(r.y));
    }
}

__global__ __launch_bounds__(1024) void kto_final(
    const float* __restrict__ tokP, const float* __restrict__ tokR,
    const int* __restrict__ Y, const unsigned char* __restrict__ pref,
    float* __restrict__ out)
{
    __shared__ float red[6][16];
    const int t = threadIdx.x;  // 0..1023
    float m0 = (Y[t]      != -100) ? 1.f : 0.f;
    float m1 = (Y[TT + t] != -100) ? 1.f : 0.f;
    float v[6];
    v[0] = m0 * tokP[t];       v[1] = m0 * tokR[t];       v[2] = m0;
    v[3] = m1 * tokP[TT + t];  v[4] = m1 * tokR[TT + t];  v[5] = m1;
#pragma unroll
    for (int d = 1; d < 64; d <<= 1)
#pragma unroll
        for (int j = 0; j < 6; ++j) v[j] += __shfl_xor(v[j], d, 64);
    int wv = threadIdx.x >> 6, ln = threadIdx.x & 63;
    if (ln == 0)
#pragma unroll
        for (int j = 0; j < 6; ++j) red[j][wv] = v[j];
    __syncthreads();
    if (t == 0) {
        float s[6];
#pragma unroll
        for (int j = 0; j < 6; ++j) { s[j] = 0.f; for (int w = 0; w < 16; ++w) s[j] += red[j][w]; }
        bool byteStorage = ((pref[1] | pref[2] | pref[3]) != 0) || (pref[4] > 1) ||
                           ((pref[5] | pref[6] | pref[7]) != 0);
        int l0, l1;
        if (byteStorage) { l0 = pref[0]; l1 = pref[1]; }
        else { l0 = ((const int*)pref)[0]; l1 = ((const int*)pref)[1]; }
        float pl0 = s[0] / fmaxf(s[2], 1.f);
        float rl0 = s[1] / fmaxf(s[2], 1.f);
        float pl1 = s[3] / fmaxf(s[5], 1.f);
        float rl1 = s[4] / fmaxf(s[5], 1.f);
        float lr0 = pl0 - rl0, lr1 = pl1 - rl1;
        float mu0 = l0 ? 1.f : -1.f;
        float mu1 = l1 ? 1.f : -1.f;
        float loss0 = 1.f - 1.f / (1.f + expf(-BETA_ * lr0 * mu0));
        float loss1 = 1.f - 1.f / (1.f + expf(-BETA_ * lr1 * mu1));
        out[0] = 0.5f * (loss0 + loss1);
    }
}

extern "C" void kernel_launch(void* const* d_in, const int* in_sizes, int n_in,
                              void* d_out, int out_size, void* d_ws, size_t ws_size,
                              hipStream_t stream) {
    const float* X  = (const float*)d_in[0];
    const float* RX = (const float*)d_in[1];
    const int*   Y  = (const int*)d_in[2];
    const unsigned char* PL = (const unsigned char*)d_in[3];
    const float* W  = (const float*)d_in[4];
    const float* RW = (const float*)d_in[5];
    float* out = (float*)d_out;

    // ws layout
    char* p = (char*)d_ws;
    float2* partP = (float2*)p;                 p += (size_t)MM * NPB * sizeof(float2);
    float2* partR = (float2*)p;                 p += (size_t)MM * NPB * sizeof(float2);
    float*  tgtP  = (float*)p;                  p += MM * sizeof(float);
    float*  tgtR  = (float*)p;                  p += MM * sizeof(float);
    float*  tokP  = (float*)p;                  p += MM * sizeof(float);
    float*  tokR  = (float*)p;                  p += MM * sizeof(float);
    unsigned short* Xbf  = (unsigned short*)p;  p += (size_t)MM * HH * 2;
    unsigned short* RXbf = (unsigned short*)p;  p += (size_t)MM * HH * 2;
    unsigned short* Wbf  = (unsigned short*)p;  p += (size_t)VV * HH * 2;
    const size_t need1 = (size_t)(p - (char*)d_ws);           // round-6 tier
    unsigned short* RWbf = (unsigned short*)p;  p += (size_t)VV * HH * 2;
    const size_t need2 = (size_t)(p - (char*)d_ws);           // fused tier

    dim3 ggrid(MM / BM, VV / BN);  // (8, 125)

    if (ws_size >= need2) {
        // tier 1 (round-12 best, 1166us): conv X/RX/W up front; GEMM-1
        // side-converts RW -> RWbf; GEMM-2 consumes RWbf.
        conv_bf16<<<512,  256, 0, stream>>>(X,  Xbf,  (int)((size_t)MM * HH / 8));
        conv_bf16<<<512,  256, 0, stream>>>(RX, RXbf, (int)((size_t)MM * HH / 8));
        conv_bf16<<<2048, 256, 0, stream>>>(W,  Wbf,  (int)((size_t)VV * HH / 8));
        kto_logits_lse_v11<true ><<<ggrid, 512, 0, stream>>>(Xbf,  Wbf,  partP, RW, RWbf);
        kto_logits_lse_v11<false><<<ggrid, 512, 0, stream>>>(RXbf, RWbf, partR, nullptr, nullptr);
    } else if (ws_size >= need1) {
        // tier 2: round-6 path (serial RW conversion into Wbf).
        conv_bf16<<<512,  256, 0, stream>>>(X,  Xbf,  (int)((size_t)MM * HH / 8));
        conv_bf16<<<512,  256, 0, stream>>>(RX, RXbf, (int)((size_t)MM * HH / 8));
        conv_bf16<<<2048, 256, 0, stream>>>(W,  Wbf,  (int)((size_t)VV * HH / 8));
        kto_logits_lse_v11<false><<<ggrid, 512, 0, stream>>>(Xbf, Wbf, partP, nullptr, nullptr);
        conv_bf16<<<2048, 256, 0, stream>>>(RW, Wbf,  (int)((size_t)VV * HH / 8));
        kto_logits_lse_v11<false><<<ggrid, 512, 0, stream>>>(RXbf, Wbf, partR, nullptr, nullptr);
    } else {
        // tier 3: fused fp32 reg-staged path (round-1, known-correct)
        dim3 fgrid(MM / 128, VV / 128);
        kto_logits_lse<<<fgrid, 256, 0, stream>>>(X,  W,  partP);
        kto_logits_lse<<<fgrid, 256, 0, stream>>>(RX, RW, partR);
    }
    kto_target<<<MM, 256, 0, stream>>>(X, RX, W, RW, Y, tgtP, tgtR);
    kto_lse_combine<<<MM, 256, 0, stream>>>(partP, partR, tgtP, tgtR, tokP, tokR);
    kto_final<<<1, 1024, 0, stream>>>(tokP, tokR, Y, PL, out);
}